// Round 8
// baseline (211.671 us; speedup 1.0000x reference)
//
#include <hip/hip_runtime.h>
#include <math.h>

#ifndef M_PI
#define M_PI 3.14159265358979323846
#endif

// out[b] = (x_b^T Ghat x_b) / (4 * mag_b),  mag = sqrt(sum x^2)+1e-7
// Ghat = (M E)^T diag(parity) (M E),  chain applied right-to-left to E,
// T kept transposed as Tt[512][2048]. Dense products: bf16 hi/lo split MFMA
// (3 products, fp32 accum), split-K=2. Split-K reduction + hi/lo convert is
// FUSED into the consumer's staging (BSRC/ASRC=1 paths) - only one standalone
// reduce remains (ghat partials -> G).

typedef __attribute__((ext_vector_type(8))) short bf16x8;
typedef __attribute__((ext_vector_type(16))) float f32x16;

// ---------------- helpers ----------------
__device__ __forceinline__ unsigned short bf16_rne(float f) {
    unsigned u = __float_as_uint(f);
    unsigned r = u + 0x7FFFu + ((u >> 16) & 1u);
    return (unsigned short)(r >> 16);
}
__device__ __forceinline__ void split2(float f, unsigned short& h, unsigned short& l) {
    h = bf16_rne(f);
    float fh = __uint_as_float(((unsigned)h) << 16);
    l = bf16_rne(f - fh);
}
__device__ __forceinline__ void async_copy16(const void* gsrc, void* ldst) {
    __builtin_amdgcn_global_load_lds(
        (const __attribute__((address_space(1))) unsigned int*)gsrc,
        (__attribute__((address_space(3))) unsigned int*)ldst,
        16, 0, 0);
}

// ---------------- merged prep ----------------
// blocks [0,2048):    kent row -> keHi/keLo + collapse row into bufT
// blocks [2048,4096): cent row -> cehi/celo
// blocks [4096,6144): X 4 rows/block -> Xhi/Xlo + mag + acc zero
// blocks [6144,6208): rotation matrices C128 (2x128x128), K16 (2x16x16)
__global__ __launch_bounds__(256) void prep_kernel(
    const float* __restrict__ X,
    const float* __restrict__ ch_ang, const float* __restrict__ k_ang,
    const float* __restrict__ cent, const float* __restrict__ kent,
    unsigned short* __restrict__ keHi, unsigned short* __restrict__ keLo,
    unsigned short* __restrict__ cehi, unsigned short* __restrict__ celo,
    unsigned short* __restrict__ Xhi, unsigned short* __restrict__ Xlo,
    float* __restrict__ mag, float* __restrict__ acc,
    float* __restrict__ bufT,
    float* __restrict__ C128, float* __restrict__ K16)
{
    __shared__ float row[2048];
    int blk = blockIdx.x;
    int tid = threadIdx.x;

    if (blk < 4096) {
        int n = blk & 2047;
        bool isk = (blk < 2048);
        const float* src = isk ? kent : cent;
        unsigned short* oh = isk ? keHi : cehi;
        unsigned short* ol = isk ? keLo : celo;
        size_t base = (size_t)n * 2048 + (size_t)tid * 8;
        float4 v0 = *(const float4*)&src[base];
        float4 v1 = *(const float4*)&src[base + 4];
        float f[8] = {v0.x, v0.y, v0.z, v0.w, v1.x, v1.y, v1.z, v1.w};
        if (isk) {
            *(float4*)&row[tid * 8] = v0;
            *(float4*)&row[tid * 8 + 4] = v1;
        }
        unsigned short h[8], l[8];
#pragma unroll
        for (int q = 0; q < 8; ++q) split2(f[q], h[q], l[q]);
        uint4 hv, lv;
        hv.x = (unsigned)h[0] | ((unsigned)h[1] << 16); hv.y = (unsigned)h[2] | ((unsigned)h[3] << 16);
        hv.z = (unsigned)h[4] | ((unsigned)h[5] << 16); hv.w = (unsigned)h[6] | ((unsigned)h[7] << 16);
        lv.x = (unsigned)l[0] | ((unsigned)l[1] << 16); lv.y = (unsigned)l[2] | ((unsigned)l[3] << 16);
        lv.z = (unsigned)l[4] | ((unsigned)l[5] << 16); lv.w = (unsigned)l[6] | ((unsigned)l[7] << 16);
        *(uint4*)&oh[base] = hv;
        *(uint4*)&ol[base] = lv;
        if (isk) {
            __syncthreads();
#pragma unroll
            for (int i = 0; i < 2; ++i) {
                int s = tid + i * 256;
                float a = 0.0f;
#pragma unroll
                for (int dj = 0; dj < 2; ++dj) {
                    int j = 2 * s + dj;
                    int m0 = ((j >> 4) << 5) | (j & 15);
                    a += row[m0] + row[m0 + 16];
                }
                bufT[(size_t)n * 512 + s] = a;
            }
        }
    } else if (blk < 6144) {
        int w = tid >> 6, lane = tid & 63;
        int b = (blk - 4096) * 4 + w;
        size_t base = (size_t)b * 512 + (size_t)lane * 8;
        float4 v0 = *(const float4*)&X[base];
        float4 v1 = *(const float4*)&X[base + 4];
        float f[8] = {v0.x, v0.y, v0.z, v0.w, v1.x, v1.y, v1.z, v1.w};
        unsigned short h[8], l[8];
#pragma unroll
        for (int q = 0; q < 8; ++q) split2(f[q], h[q], l[q]);
        uint4 hv, lv;
        hv.x = (unsigned)h[0] | ((unsigned)h[1] << 16); hv.y = (unsigned)h[2] | ((unsigned)h[3] << 16);
        hv.z = (unsigned)h[4] | ((unsigned)h[5] << 16); hv.w = (unsigned)h[6] | ((unsigned)h[7] << 16);
        lv.x = (unsigned)l[0] | ((unsigned)l[1] << 16); lv.y = (unsigned)l[2] | ((unsigned)l[3] << 16);
        lv.z = (unsigned)l[4] | ((unsigned)l[5] << 16); lv.w = (unsigned)l[6] | ((unsigned)l[7] << 16);
        *(uint4*)&Xhi[base] = hv;
        *(uint4*)&Xlo[base] = lv;
        float ss = 0.0f;
#pragma unroll
        for (int q = 0; q < 8; ++q) ss += f[q] * f[q];
#pragma unroll
        for (int off = 32; off; off >>= 1) ss += __shfl_xor(ss, off, 64);
        if (lane == 0) {
            mag[b] = sqrtf(ss) + 1e-7f;
            acc[b] = 0.0f;
        }
    } else {
        int t = (blk - 6144) * 256 + tid;
        int stride = 64 * 256;
        for (int idx = t; idx < 2 * 128 * 128; idx += stride) {
            int l = idx >> 14;
            int rem = idx & 16383;
            int a = rem >> 7, b = rem & 127;
            float p = 1.0f;
#pragma unroll
            for (int q = 0; q < 7; ++q) {
                float half = ch_ang[l * 7 + q] * (float)M_PI;
                float c = cosf(half), s = sinf(half);
                int ia = (a >> (6 - q)) & 1;
                int ib = (b >> (6 - q)) & 1;
                float e = ia ? (ib ? c : s) : (ib ? -s : c);
                p *= e;
            }
            C128[idx] = p;
        }
        for (int idx = t; idx < 2 * 16 * 16; idx += stride) {
            int l = idx >> 8;
            int rem = idx & 255;
            int a = rem >> 4, b = rem & 15;
            float p = 1.0f;
#pragma unroll
            for (int q = 0; q < 4; ++q) {
                float half = k_ang[l * 4 + q] * 0.5f;
                float c = cosf(half), s = sinf(half);
                int ia = (a >> (3 - q)) & 1;
                int ib = (b >> (3 - q)) & 1;
                float e = ia ? (ib ? c : s) : (ib ? -s : c);
                p *= e;
            }
            K16[idx] = p;
        }
    }
}

// ---------------- transpose T[2048][512] -> Tt hi/lo [512][2048], kr1 fused ----------------
__global__ __launch_bounds__(256) void transpose_convert_kernel(const float* __restrict__ T,
                                                                const float* __restrict__ K16l,
                                                                unsigned short* __restrict__ Hi,
                                                                unsigned short* __restrict__ Lo)
{
    __shared__ float tile[64][65];
    int n0 = blockIdx.x * 64, s0 = blockIdx.y * 64;
    int tid = threadIdx.x;
#pragma unroll
    for (int p = 0; p < 4; ++p) {
        int lin = tid + p * 256;
        int r = lin >> 4, c4 = lin & 15;
        float4 v = *(const float4*)&T[(size_t)(n0 + r) * 512 + s0 + c4 * 4];
        tile[r][c4 * 4 + 0] = v.x; tile[r][c4 * 4 + 1] = v.y;
        tile[r][c4 * 4 + 2] = v.z; tile[r][c4 * 4 + 3] = v.w;
    }
    __syncthreads();
    if (n0 == 1984) {
        float o[16];
        if (tid < 64) {
#pragma unroll
            for (int i = 0; i < 16; ++i) {
                float a = 0.0f;
#pragma unroll
                for (int j = 0; j < 16; ++j) a += K16l[i * 16 + j] * tile[48 + j][tid];
                o[i] = a;
            }
        }
        __syncthreads();
        if (tid < 64) {
#pragma unroll
            for (int i = 0; i < 16; ++i) tile[48 + i][tid] = o[i];
        }
        __syncthreads();
    }
#pragma unroll
    for (int p = 0; p < 4; ++p) {
        int lin = tid + p * 256;
        int sl = lin >> 4, j4 = lin & 15;
        unsigned short h[4], l[4];
#pragma unroll
        for (int q = 0; q < 4; ++q) split2(tile[j4 * 4 + q][sl], h[q], l[q]);
        size_t o = (size_t)(s0 + sl) * 2048 + n0 + j4 * 4;
        *(uint2*)&Hi[o] = make_uint2((unsigned)h[0] | ((unsigned)h[1] << 16),
                                     (unsigned)h[2] | ((unsigned)h[3] << 16));
        *(uint2*)&Lo[o] = make_uint2((unsigned)l[0] | ((unsigned)l[1] << 16),
                                     (unsigned)l[2] | ((unsigned)l[3] << 16));
    }
}

// ---------------- chrot (+optional krot) reading split-K PARTIAL PAIRS -> hi/lo bf16 ----------------
__global__ __launch_bounds__(256) void chrot_t_kernel(const float* __restrict__ C,
                                                      const float* __restrict__ K16l,  // may be null
                                                      const float* __restrict__ in0,
                                                      const float* __restrict__ in1,
                                                      unsigned short* __restrict__ outH,
                                                      unsigned short* __restrict__ outL)
{
    __shared__ float row[2048];
    __shared__ float orow[2048];
    int s = blockIdx.x;
    int tid = threadIdx.x;
    for (int i = tid; i < 512; i += 256) {
        float4 a = *(const float4*)&in0[(size_t)s * 2048 + i * 4];
        float4 b = *(const float4*)&in1[(size_t)s * 2048 + i * 4];
        a.x += b.x; a.y += b.y; a.z += b.z; a.w += b.w;
        *(float4*)&row[i * 4] = a;
    }
    __syncthreads();
    int a = tid >> 1, th = (tid & 1) * 8;
    float res[8];
#pragma unroll
    for (int j = 0; j < 8; ++j) res[j] = 0.0f;
    for (int ap = 0; ap < 128; ++ap) {
        float c = C[a * 128 + ap];
#pragma unroll
        for (int j = 0; j < 8; ++j) res[j] += c * row[ap * 16 + th + j];
    }
#pragma unroll
    for (int j = 0; j < 8; ++j) orow[a * 16 + th + j] = res[j];
    __syncthreads();
    if (K16l) {
        float o = 0.0f;
        if (tid < 16) {
#pragma unroll
            for (int j = 0; j < 16; ++j) o += K16l[tid * 16 + j] * orow[2032 + j];
        }
        __syncthreads();
        if (tid < 16) orow[2032 + tid] = o;
        __syncthreads();
    }
    size_t base = (size_t)s * 2048 + (size_t)tid * 8;
    unsigned short h[8], l[8];
#pragma unroll
    for (int q = 0; q < 8; ++q) split2(orow[tid * 8 + q], h[q], l[q]);
    uint4 hv, lv;
    hv.x = (unsigned)h[0] | ((unsigned)h[1] << 16); hv.y = (unsigned)h[2] | ((unsigned)h[3] << 16);
    hv.z = (unsigned)h[4] | ((unsigned)h[5] << 16); hv.w = (unsigned)h[6] | ((unsigned)h[7] << 16);
    lv.x = (unsigned)l[0] | ((unsigned)l[1] << 16); lv.y = (unsigned)l[2] | ((unsigned)l[3] << 16);
    lv.z = (unsigned)l[4] | ((unsigned)l[5] << 16); lv.w = (unsigned)l[6] | ((unsigned)l[7] << 16);
    *(uint4*)&outH[base] = hv;
    *(uint4*)&outL[base] = lv;
}

// ---------------- reduce split-K partials -> hi/lo (ghat output only) ----------------
__global__ __launch_bounds__(256) void reduce_hl_kernel(const float* __restrict__ P, int nchunks, int csize,
                                                        unsigned short* __restrict__ outH,
                                                        unsigned short* __restrict__ outL)
{
    int i4 = blockIdx.x * 256 + threadIdx.x;
    size_t base = (size_t)i4 * 4;
    float4 v = *(const float4*)&P[base];
    for (int c = 1; c < nchunks; ++c) {
        float4 u = *(const float4*)&P[(size_t)c * csize + base];
        v.x += u.x; v.y += u.y; v.z += u.z; v.w += u.w;
    }
    float f[4] = {v.x, v.y, v.z, v.w};
    unsigned short h[4], l[4];
#pragma unroll
    for (int q = 0; q < 4; ++q) split2(f[q], h[q], l[q]);
    *(uint2*)&outH[base] = make_uint2((unsigned)h[0] | ((unsigned)h[1] << 16),
                                      (unsigned)h[2] | ((unsigned)h[3] << 16));
    *(uint2*)&outL[base] = make_uint2((unsigned)l[0] | ((unsigned)l[1] << 16),
                                      (unsigned)l[2] | ((unsigned)l[3] << 16));
}

// ---------------- hi/lo split bf16 MFMA GEMM ----------------
// C[M,N] = A[M,K]@B^T[N,K]; 64x64 tile, 256 threads, 4-wave k-split, K_STEP=64,
// double-buffered 64KB LDS, prefetch-before-compute pipeline.
// ASRC/BSRC: 0 = bf16 hi/lo via async global_load_lds
//            1 = fp32 split-K partial PAIR, reg-staged: load early, sum+convert+
//                ds_write after MFMA (fused reduction)
//            2 = like 1 plus parity sign-flip by global k index (ghat B side)
// EPI 3: fp32 transposed partials into Cout + kc*M*N
// EPI 4: fused row-dot: atomicAdd(accOut[bm*64+row], sum_col Ytile*X)
template<int EPI, int ASRC, int BSRC>
__global__ __launch_bounds__(256) void gemm_hl_kernel(
    const unsigned short* __restrict__ Ahi, const unsigned short* __restrict__ Alo,
    const float* __restrict__ Af32, int ldA,
    const unsigned short* __restrict__ Bhi, const unsigned short* __restrict__ Blo,
    const float* __restrict__ Bf32, int ldB,
    int csize,
    float* __restrict__ Cout,
    const float* __restrict__ Xf, float* __restrict__ accOut,
    int M, int N, int Kchunk)
{
    __shared__ __align__(16) char smem[65536];  // 2 buffers x (Ah|Al|Bh|Bl, 8KB each)
    const int tid = threadIdx.x;
    const int lane = tid & 63;
    const int w = tid >> 6;
    const int bm = blockIdx.x, bn = blockIdx.y, kc = blockIdx.z;
    const int kbase = kc * Kchunk;

    f32x16 acc[2][2];
#pragma unroll
    for (int i = 0; i < 2; ++i)
#pragma unroll
        for (int j = 0; j < 2; ++j)
#pragma unroll
            for (int q = 0; q < 16; ++q) acc[i][j][q] = 0.0f;

    const int col = lane & 31;
    const int hi = lane >> 5;
    const int k16 = w * 16;
    int aaddr[2];
#pragma unroll
    for (int ms = 0; ms < 2; ++ms) {
        int row = ms * 32 + col;
        int cb = (k16 + hi * 8) * 2;
        aaddr[ms] = row * 128 + (cb ^ ((row & 7) << 4));
    }
    // staging slot mapping (identical bytes/layout for async and reg paths)
    int srow[2], sge[2], sdst[2], sdfull[2];
#pragma unroll
    for (int p = 0; p < 2; ++p) {
        int slot = p * 4096 + tid * 16;
        int r = slot >> 7;
        int pc = slot & 127;
        int lc = pc ^ ((r & 7) << 4);
        srow[p] = r;
        sge[p] = lc >> 1;
        sdst[p] = p * 4096 + w * 1024;    // wave base for global_load_lds
        sdfull[p] = slot;                 // full per-lane byte offset for ds_write
    }

    float4 ar0[2], ar1[2], ar2[2], ar3[2];   // A pair regs (ASRC==1)
    float4 br0[2], br1[2], br2[2], br3[2];   // B pair regs (BSRC>=1)
    int stagedKG = 0;

#define STAGE_A_ASYNC(BUF, KG)                                                             \
    {                                                                                      \
        _Pragma("unroll")                                                                  \
        for (int p = 0; p < 2; ++p) {                                                      \
            int ge = (KG) + sge[p];                                                        \
            async_copy16(Ahi + (size_t)(bm * 64 + srow[p]) * ldA + ge,                     \
                         &smem[(BUF) * 32768 + 0 + sdst[p]]);                              \
            async_copy16(Alo + (size_t)(bm * 64 + srow[p]) * ldA + ge,                     \
                         &smem[(BUF) * 32768 + 8192 + sdst[p]]);                           \
        }                                                                                  \
    }
#define STAGE_B_ASYNC(BUF, KG)                                                             \
    {                                                                                      \
        _Pragma("unroll")                                                                  \
        for (int p = 0; p < 2; ++p) {                                                      \
            int ge = (KG) + sge[p];                                                        \
            async_copy16(Bhi + (size_t)(bn * 64 + srow[p]) * ldB + ge,                     \
                         &smem[(BUF) * 32768 + 16384 + sdst[p]]);                          \
            async_copy16(Blo + (size_t)(bn * 64 + srow[p]) * ldB + ge,                     \
                         &smem[(BUF) * 32768 + 24576 + sdst[p]]);                          \
        }                                                                                  \
    }
#define LOADF_A(KG)                                                                        \
    {                                                                                      \
        _Pragma("unroll")                                                                  \
        for (int p = 0; p < 2; ++p) {                                                      \
            size_t ad = (size_t)(bm * 64 + srow[p]) * ldA + (KG) + sge[p];                 \
            ar0[p] = *(const float4*)&Af32[ad];                                            \
            ar1[p] = *(const float4*)&Af32[ad + 4];                                        \
            ar2[p] = *(const float4*)&Af32[ad + (size_t)csize];                            \
            ar3[p] = *(const float4*)&Af32[ad + (size_t)csize + 4];                        \
        }                                                                                  \
    }
#define LOADF_B(KG)                                                                        \
    {                                                                                      \
        _Pragma("unroll")                                                                  \
        for (int p = 0; p < 2; ++p) {                                                      \
            size_t ad = (size_t)(bn * 64 + srow[p]) * ldB + (KG) + sge[p];                 \
            br0[p] = *(const float4*)&Bf32[ad];                                            \
            br1[p] = *(const float4*)&Bf32[ad + 4];                                        \
            br2[p] = *(const float4*)&Bf32[ad + (size_t)csize];                            \
            br3[p] = *(const float4*)&Bf32[ad + (size_t)csize + 4];                        \
        }                                                                                  \
    }
#define WRITE_CONV(BUF, R0, R1, R2, R3, OFFH, OFFL, PAR)                                   \
    {                                                                                      \
        _Pragma("unroll")                                                                  \
        for (int p = 0; p < 2; ++p) {                                                      \
            float f[8] = {R0[p].x + R2[p].x, R0[p].y + R2[p].y,                            \
                          R0[p].z + R2[p].z, R0[p].w + R2[p].w,                            \
                          R1[p].x + R3[p].x, R1[p].y + R3[p].y,                            \
                          R1[p].z + R3[p].z, R1[p].w + R3[p].w};                           \
            unsigned short h[8], l[8];                                                     \
            _Pragma("unroll")                                                              \
            for (int q = 0; q < 8; ++q) {                                                  \
                split2(f[q], h[q], l[q]);                                                  \
                if (PAR) {                                                                 \
                    int n = stagedKG + sge[p] + q;                                         \
                    unsigned short flip = (unsigned short)(((unsigned)(__popc(n) & 1)) << 15); \
                    h[q] ^= flip; l[q] ^= flip;                                            \
                }                                                                          \
            }                                                                              \
            uint4 hv, lv;                                                                  \
            hv.x = (unsigned)h[0] | ((unsigned)h[1] << 16);                                \
            hv.y = (unsigned)h[2] | ((unsigned)h[3] << 16);                                \
            hv.z = (unsigned)h[4] | ((unsigned)h[5] << 16);                                \
            hv.w = (unsigned)h[6] | ((unsigned)h[7] << 16);                                \
            lv.x = (unsigned)l[0] | ((unsigned)l[1] << 16);                                \
            lv.y = (unsigned)l[2] | ((unsigned)l[3] << 16);                                \
            lv.z = (unsigned)l[4] | ((unsigned)l[5] << 16);                                \
            lv.w = (unsigned)l[6] | ((unsigned)l[7] << 16);                                \
            *(uint4*)&smem[(BUF) * 32768 + (OFFH) + sdfull[p]] = hv;                       \
            *(uint4*)&smem[(BUF) * 32768 + (OFFL) + sdfull[p]] = lv;                       \
        }                                                                                  \
    }

    const int nsteps = Kchunk >> 6;
    // ---- prologue: stage tile 0
    if (ASRC == 0) STAGE_A_ASYNC(0, kbase);
    if (BSRC == 0) STAGE_B_ASYNC(0, kbase);
    if (ASRC == 1) LOADF_A(kbase);
    if (BSRC >= 1) LOADF_B(kbase);
    stagedKG = kbase;
    asm volatile("s_waitcnt vmcnt(0)" ::: "memory");
    if (ASRC == 1) WRITE_CONV(0, ar0, ar1, ar2, ar3, 0, 8192, 0);
    if (BSRC >= 1) WRITE_CONV(0, br0, br1, br2, br3, 16384, 24576, (BSRC == 2));
    if (ASRC == 1 || BSRC >= 1) asm volatile("s_waitcnt lgkmcnt(0)" ::: "memory");
    __builtin_amdgcn_s_barrier();
    __builtin_amdgcn_sched_barrier(0);

    int cur = 0;
    for (int kt = 0; kt < nsteps; ++kt) {
        const bool havenext = (kt + 1 < nsteps);
        const int kgn = kbase + ((kt + 1) << 6);
        if (havenext) {
            if (ASRC == 0) STAGE_A_ASYNC(cur ^ 1, kgn);
            if (BSRC == 0) STAGE_B_ASYNC(cur ^ 1, kgn);
            if (ASRC == 1) LOADF_A(kgn);
            if (BSRC >= 1) LOADF_B(kgn);
        }
        __builtin_amdgcn_sched_barrier(0);
        const char* base = &smem[cur * 32768];
        bf16x8 ah[2], al[2], bh[2], bl[2];
#pragma unroll
        for (int ms = 0; ms < 2; ++ms) {
            ah[ms] = *(const bf16x8*)(base + 0 + aaddr[ms]);
            al[ms] = *(const bf16x8*)(base + 8192 + aaddr[ms]);
        }
#pragma unroll
        for (int ns = 0; ns < 2; ++ns) {
            bh[ns] = *(const bf16x8*)(base + 16384 + aaddr[ns]);
            bl[ns] = *(const bf16x8*)(base + 24576 + aaddr[ns]);
        }
#pragma unroll
        for (int ms = 0; ms < 2; ++ms)
#pragma unroll
            for (int ns = 0; ns < 2; ++ns) {
                acc[ms][ns] = __builtin_amdgcn_mfma_f32_32x32x16_bf16(ah[ms], bh[ns], acc[ms][ns], 0, 0, 0);
                acc[ms][ns] = __builtin_amdgcn_mfma_f32_32x32x16_bf16(ah[ms], bl[ns], acc[ms][ns], 0, 0, 0);
                acc[ms][ns] = __builtin_amdgcn_mfma_f32_32x32x16_bf16(al[ms], bh[ns], acc[ms][ns], 0, 0, 0);
            }
        __builtin_amdgcn_sched_barrier(0);
        if (havenext) {
            asm volatile("s_waitcnt vmcnt(0)" ::: "memory");   // async staged + reg loads landed
            stagedKG = kgn;
            if (ASRC == 1) WRITE_CONV(cur ^ 1, ar0, ar1, ar2, ar3, 0, 8192, 0);
            if (BSRC >= 1) WRITE_CONV(cur ^ 1, br0, br1, br2, br3, 16384, 24576, (BSRC == 2));
            if (ASRC == 1 || BSRC >= 1) asm volatile("s_waitcnt lgkmcnt(0)" ::: "memory");
        }
        __builtin_amdgcn_s_barrier();
        __builtin_amdgcn_sched_barrier(0);
        cur ^= 1;
    }
#undef STAGE_A_ASYNC
#undef STAGE_B_ASYNC
#undef LOADF_A
#undef LOADF_B
#undef WRITE_CONV

    // 4-wave k-split tree reduction through LDS
    float* red = (float*)smem;
    if (w >= 2) {
        float* dst = red + (w - 2) * 4096;
#pragma unroll
        for (int ms = 0; ms < 2; ++ms)
#pragma unroll
            for (int ns = 0; ns < 2; ++ns)
#pragma unroll
                for (int r = 0; r < 16; ++r) {
                    int rowr = (r & 3) + 8 * (r >> 2) + 4 * hi;
                    dst[(ms * 32 + rowr) * 64 + ns * 32 + col] = acc[ms][ns][r];
                }
    }
    __syncthreads();
    if (w < 2) {
        float* src = red + w * 4096;
#pragma unroll
        for (int ms = 0; ms < 2; ++ms)
#pragma unroll
            for (int ns = 0; ns < 2; ++ns)
#pragma unroll
                for (int r = 0; r < 16; ++r) {
                    int rowr = (r & 3) + 8 * (r >> 2) + 4 * hi;
                    acc[ms][ns][r] += src[(ms * 32 + rowr) * 64 + ns * 32 + col];
                }
    }
    __syncthreads();
    if (w == 1) {
#pragma unroll
        for (int ms = 0; ms < 2; ++ms)
#pragma unroll
            for (int ns = 0; ns < 2; ++ns)
#pragma unroll
                for (int r = 0; r < 16; ++r) {
                    int rowr = (r & 3) + 8 * (r >> 2) + 4 * hi;
                    red[(ms * 32 + rowr) * 64 + ns * 32 + col] = acc[ms][ns][r];
                }
    }
    __syncthreads();
    if (w == 0) {
#pragma unroll
        for (int ms = 0; ms < 2; ++ms)
#pragma unroll
            for (int ns = 0; ns < 2; ++ns)
#pragma unroll
                for (int r = 0; r < 16; ++r) {
                    int rowr = (r & 3) + 8 * (r >> 2) + 4 * hi;
                    acc[ms][ns][r] += red[(ms * 32 + rowr) * 64 + ns * 32 + col];
                }
        if (EPI == 3) {
            float* dstC = Cout + (size_t)kc * M * N;
#pragma unroll
            for (int ms = 0; ms < 2; ++ms)
#pragma unroll
                for (int ns = 0; ns < 2; ++ns)
#pragma unroll
                    for (int g = 0; g < 4; ++g) {
                        int rowt = ms * 32 + 8 * g + 4 * hi;
                        float4 v = make_float4(acc[ms][ns][4 * g + 0], acc[ms][ns][4 * g + 1],
                                               acc[ms][ns][4 * g + 2], acc[ms][ns][4 * g + 3]);
                        *(float4*)&dstC[(size_t)(bn * 64 + ns * 32 + col) * M + bm * 64 + rowt] = v;
                    }
        }
        if (EPI == 4) {
#pragma unroll
            for (int ms = 0; ms < 2; ++ms)
#pragma unroll
                for (int ns = 0; ns < 2; ++ns)
#pragma unroll
                    for (int r = 0; r < 16; ++r) {
                        int rowr = (r & 3) + 8 * (r >> 2) + 4 * hi;
                        red[(ms * 32 + rowr) * 64 + ns * 32 + col] = acc[ms][ns][r];
                    }
        }
    }
    if (EPI == 4) {
        __syncthreads();
        int row = tid >> 2, q = tid & 3;
        const float* xrow = Xf + (size_t)(bm * 64 + row) * 512 + bn * 64 + q * 16;
        const float* yr = &red[row * 64 + q * 16];
        float s = 0.0f;
#pragma unroll
        for (int j4 = 0; j4 < 4; ++j4) {
            float4 x = *(const float4*)&xrow[j4 * 4];
            s += x.x * yr[j4 * 4 + 0] + x.y * yr[j4 * 4 + 1] +
                 x.z * yr[j4 * 4 + 2] + x.w * yr[j4 * 4 + 3];
        }
        s += __shfl_xor(s, 1, 64);
        s += __shfl_xor(s, 2, 64);
        if (q == 0) atomicAdd(&accOut[bm * 64 + row], s);
    }
}

// ---------------- out[b] = acc[b] / (4*mag[b]) ----------------
__global__ __launch_bounds__(256) void divide_kernel(const float* __restrict__ acc,
                                                     const float* __restrict__ mag,
                                                     float* __restrict__ out)
{
    int b = blockIdx.x * 256 + threadIdx.x;
    out[b] = acc[b] / (4.0f * mag[b]);
}

// ================= launcher =================
extern "C" void kernel_launch(void* const* d_in, const int* in_sizes, int n_in,
                              void* d_out, int out_size, void* d_ws, size_t ws_size,
                              hipStream_t stream)
{
    const float* X = (const float*)d_in[0];
    const float* chang = (const float*)d_in[1];
    const float* kang = (const float*)d_in[2];
    const float* cent = (const float*)d_in[3];
    const float* kent = (const float*)d_in[4];
    float* out = (float*)d_out;

    size_t off = 0;
    auto alloc = [&](size_t bytes) -> char* {
        char* p = (char*)d_ws + off;
        off += (bytes + 255) & ~(size_t)255;
        return p;
    };
    const int CS = 2048 * 512;                               // partial chunk (floats)
    float* bufT = (float*)alloc(2048 * 512 * 4);             // T0 fp32
    float* Pa = (float*)alloc(2 * CS * 4);                   // split-K partials A
    float* Pb = (float*)alloc(2 * CS * 4);                   // split-K partials B
    float* PG = (float*)alloc(8 * 512 * 512 * 4);            // ghat partials
    float* C128 = (float*)alloc(2 * 128 * 128 * 4);
    float* K16 = (float*)alloc(2 * 16 * 16 * 4);
    float* mag = (float*)alloc(8192 * 4);
    float* acc = (float*)alloc(8192 * 4);
    unsigned short* T0hi = (unsigned short*)alloc(512 * 2048 * 2);
    unsigned short* T0lo = (unsigned short*)alloc(512 * 2048 * 2);
    unsigned short* Ghi = (unsigned short*)alloc(512 * 512 * 2);
    unsigned short* Glo = (unsigned short*)alloc(512 * 512 * 2);
    unsigned short* Xhi = (unsigned short*)alloc(8192 * 512 * 2);
    unsigned short* Xlo = (unsigned short*)alloc(8192 * 512 * 2);
    unsigned short* keHi = (unsigned short*)alloc(2048 * 2048 * 2);
    unsigned short* keLo = (unsigned short*)alloc(2048 * 2048 * 2);
    unsigned short* cehi = (unsigned short*)alloc(2048 * 2048 * 2);
    unsigned short* celo = (unsigned short*)alloc(2048 * 2048 * 2);
    (void)ws_size;

    prep_kernel<<<6208, 256, 0, stream>>>(X, chang, kang, cent, kent,
                                          keHi, keLo, cehi, celo,
                                          Xhi, Xlo, mag, acc, bufT, C128, K16);
    transpose_convert_kernel<<<dim3(32, 8), 256, 0, stream>>>(bufT, K16 + 256, T0hi, T0lo);

    // G1: kent @ T0 -> Pa (split-K=2 partials)
    gemm_hl_kernel<3, 0, 0><<<dim3(32, 8, 2), 256, 0, stream>>>(
        keHi, keLo, nullptr, 2048, T0hi, T0lo, nullptr, 2048, CS,
        Pa, nullptr, nullptr, 2048, 512, 1024);
    // G2: cent @ (Pa pair, fused reduce+convert) -> Pb
    gemm_hl_kernel<3, 0, 1><<<dim3(32, 8, 2), 256, 0, stream>>>(
        cehi, celo, nullptr, 2048, nullptr, nullptr, Pa, 2048, CS,
        Pb, nullptr, nullptr, 2048, 512, 1024);
    // ch1 + kr0 on (Pb pair) -> T0hi/lo
    chrot_t_kernel<<<512, 256, 0, stream>>>(C128 + 16384, K16, Pb, Pb + CS, T0hi, T0lo);
    // G3: kent @ T0 -> Pa
    gemm_hl_kernel<3, 0, 0><<<dim3(32, 8, 2), 256, 0, stream>>>(
        keHi, keLo, nullptr, 2048, T0hi, T0lo, nullptr, 2048, CS,
        Pa, nullptr, nullptr, 2048, 512, 1024);
    // G4: cent @ (Pa pair) -> Pb
    gemm_hl_kernel<3, 0, 1><<<dim3(32, 8, 2), 256, 0, stream>>>(
        cehi, celo, nullptr, 2048, nullptr, nullptr, Pa, 2048, CS,
        Pb, nullptr, nullptr, 2048, 512, 1024);
    // ch0 on (Pb pair) -> T0hi/lo
    chrot_t_kernel<<<512, 256, 0, stream>>>(C128, nullptr, Pb, Pb + CS, T0hi, T0lo);
    // G5: cent @ T0 -> Pa  (= T5 partials)
    gemm_hl_kernel<3, 0, 0><<<dim3(32, 8, 2), 256, 0, stream>>>(
        cehi, celo, nullptr, 2048, T0hi, T0lo, nullptr, 2048, CS,
        Pa, nullptr, nullptr, 2048, 512, 1024);
    // ghat: A = (Pa pair), B = (Pa pair + parity), split-K=8 -> PG
    gemm_hl_kernel<3, 1, 2><<<dim3(8, 8, 8), 256, 0, stream>>>(
        nullptr, nullptr, Pa, 2048, nullptr, nullptr, Pa, 2048, CS,
        PG, nullptr, nullptr, 512, 512, 256);
    reduce_hl_kernel<<<256, 256, 0, stream>>>(PG, 8, 512 * 512, Ghi, Glo);
    // final: fused X@G^T row-dot -> acc
    gemm_hl_kernel<4, 0, 0><<<dim3(128, 8, 1), 256, 0, stream>>>(
        Xhi, Xlo, nullptr, 512, Ghi, Glo, nullptr, 512, 0,
        nullptr, X, acc, 8192, 512, 512);
    divide_kernel<<<32, 256, 0, stream>>>(acc, mag, out);
}

// Round 9
// 205.266 us; speedup vs baseline: 1.0312x; 1.0312x over previous
//
#include <hip/hip_runtime.h>
#include <math.h>

#ifndef M_PI
#define M_PI 3.14159265358979323846
#endif

// out[b] = (x_b^T Ghat x_b) / (4 * mag_b),  mag = sqrt(sum x^2)+1e-7
// Ghat = (M E)^T diag(parity) (M E),  chain applied right-to-left to E,
// T kept transposed as Tt[512][2048]. Dense products: bf16 hi/lo split MFMA
// (3 products, fp32 accum). Chain GEMMs split-K=2 for 2 blocks/CU co-residency;
// s_setprio(1) wrapped around the MFMA cluster (T5: co-resident blocks are at
// different pipeline phases, scheduler favors the MFMA-issuing wave).

typedef __attribute__((ext_vector_type(8))) short bf16x8;
typedef __attribute__((ext_vector_type(16))) float f32x16;

// ---------------- helpers ----------------
__device__ __forceinline__ unsigned short bf16_rne(float f) {
    unsigned u = __float_as_uint(f);
    unsigned r = u + 0x7FFFu + ((u >> 16) & 1u);
    return (unsigned short)(r >> 16);
}
__device__ __forceinline__ void split2(float f, unsigned short& h, unsigned short& l) {
    h = bf16_rne(f);
    float fh = __uint_as_float(((unsigned)h) << 16);
    l = bf16_rne(f - fh);
}
__device__ __forceinline__ void async_copy16(const void* gsrc, void* ldst) {
    __builtin_amdgcn_global_load_lds(
        (const __attribute__((address_space(1))) unsigned int*)gsrc,
        (__attribute__((address_space(3))) unsigned int*)ldst,
        16, 0, 0);
}

// ---------------- merged prep ----------------
// blocks [0,2048):    kent row -> keHi/keLo + collapse row into bufT
// blocks [2048,4096): cent row -> cehi/celo
// blocks [4096,6144): X 4 rows/block -> Xhi/Xlo + mag + acc zero
// blocks [6144,6208): rotation matrices C128 (2x128x128), K16 (2x16x16)
__global__ __launch_bounds__(256) void prep_kernel(
    const float* __restrict__ X,
    const float* __restrict__ ch_ang, const float* __restrict__ k_ang,
    const float* __restrict__ cent, const float* __restrict__ kent,
    unsigned short* __restrict__ keHi, unsigned short* __restrict__ keLo,
    unsigned short* __restrict__ cehi, unsigned short* __restrict__ celo,
    unsigned short* __restrict__ Xhi, unsigned short* __restrict__ Xlo,
    float* __restrict__ mag, float* __restrict__ acc,
    float* __restrict__ bufT,
    float* __restrict__ C128, float* __restrict__ K16)
{
    __shared__ float row[2048];
    int blk = blockIdx.x;
    int tid = threadIdx.x;

    if (blk < 4096) {
        int n = blk & 2047;
        bool isk = (blk < 2048);
        const float* src = isk ? kent : cent;
        unsigned short* oh = isk ? keHi : cehi;
        unsigned short* ol = isk ? keLo : celo;
        size_t base = (size_t)n * 2048 + (size_t)tid * 8;
        float4 v0 = *(const float4*)&src[base];
        float4 v1 = *(const float4*)&src[base + 4];
        float f[8] = {v0.x, v0.y, v0.z, v0.w, v1.x, v1.y, v1.z, v1.w};
        if (isk) {
            *(float4*)&row[tid * 8] = v0;
            *(float4*)&row[tid * 8 + 4] = v1;
        }
        unsigned short h[8], l[8];
#pragma unroll
        for (int q = 0; q < 8; ++q) split2(f[q], h[q], l[q]);
        uint4 hv, lv;
        hv.x = (unsigned)h[0] | ((unsigned)h[1] << 16); hv.y = (unsigned)h[2] | ((unsigned)h[3] << 16);
        hv.z = (unsigned)h[4] | ((unsigned)h[5] << 16); hv.w = (unsigned)h[6] | ((unsigned)h[7] << 16);
        lv.x = (unsigned)l[0] | ((unsigned)l[1] << 16); lv.y = (unsigned)l[2] | ((unsigned)l[3] << 16);
        lv.z = (unsigned)l[4] | ((unsigned)l[5] << 16); lv.w = (unsigned)l[6] | ((unsigned)l[7] << 16);
        *(uint4*)&oh[base] = hv;
        *(uint4*)&ol[base] = lv;
        if (isk) {
            __syncthreads();
#pragma unroll
            for (int i = 0; i < 2; ++i) {
                int s = tid + i * 256;
                float a = 0.0f;
#pragma unroll
                for (int dj = 0; dj < 2; ++dj) {
                    int j = 2 * s + dj;
                    int m0 = ((j >> 4) << 5) | (j & 15);
                    a += row[m0] + row[m0 + 16];
                }
                bufT[(size_t)n * 512 + s] = a;
            }
        }
    } else if (blk < 6144) {
        int w = tid >> 6, lane = tid & 63;
        int b = (blk - 4096) * 4 + w;
        size_t base = (size_t)b * 512 + (size_t)lane * 8;
        float4 v0 = *(const float4*)&X[base];
        float4 v1 = *(const float4*)&X[base + 4];
        float f[8] = {v0.x, v0.y, v0.z, v0.w, v1.x, v1.y, v1.z, v1.w};
        unsigned short h[8], l[8];
#pragma unroll
        for (int q = 0; q < 8; ++q) split2(f[q], h[q], l[q]);
        uint4 hv, lv;
        hv.x = (unsigned)h[0] | ((unsigned)h[1] << 16); hv.y = (unsigned)h[2] | ((unsigned)h[3] << 16);
        hv.z = (unsigned)h[4] | ((unsigned)h[5] << 16); hv.w = (unsigned)h[6] | ((unsigned)h[7] << 16);
        lv.x = (unsigned)l[0] | ((unsigned)l[1] << 16); lv.y = (unsigned)l[2] | ((unsigned)l[3] << 16);
        lv.z = (unsigned)l[4] | ((unsigned)l[5] << 16); lv.w = (unsigned)l[6] | ((unsigned)l[7] << 16);
        *(uint4*)&Xhi[base] = hv;
        *(uint4*)&Xlo[base] = lv;
        float ss = 0.0f;
#pragma unroll
        for (int q = 0; q < 8; ++q) ss += f[q] * f[q];
#pragma unroll
        for (int off = 32; off; off >>= 1) ss += __shfl_xor(ss, off, 64);
        if (lane == 0) {
            mag[b] = sqrtf(ss) + 1e-7f;
            acc[b] = 0.0f;
        }
    } else {
        int t = (blk - 6144) * 256 + tid;
        int stride = 64 * 256;
        for (int idx = t; idx < 2 * 128 * 128; idx += stride) {
            int l = idx >> 14;
            int rem = idx & 16383;
            int a = rem >> 7, b = rem & 127;
            float p = 1.0f;
#pragma unroll
            for (int q = 0; q < 7; ++q) {
                float half = ch_ang[l * 7 + q] * (float)M_PI;
                float c = cosf(half), s = sinf(half);
                int ia = (a >> (6 - q)) & 1;
                int ib = (b >> (6 - q)) & 1;
                float e = ia ? (ib ? c : s) : (ib ? -s : c);
                p *= e;
            }
            C128[idx] = p;
        }
        for (int idx = t; idx < 2 * 16 * 16; idx += stride) {
            int l = idx >> 8;
            int rem = idx & 255;
            int a = rem >> 4, b = rem & 15;
            float p = 1.0f;
#pragma unroll
            for (int q = 0; q < 4; ++q) {
                float half = k_ang[l * 4 + q] * 0.5f;
                float c = cosf(half), s = sinf(half);
                int ia = (a >> (3 - q)) & 1;
                int ib = (b >> (3 - q)) & 1;
                float e = ia ? (ib ? c : s) : (ib ? -s : c);
                p *= e;
            }
            K16[idx] = p;
        }
    }
}

// ---------------- transpose T[2048][512] -> Tt hi/lo [512][2048], kr1 fused ----------------
__global__ __launch_bounds__(256) void transpose_convert_kernel(const float* __restrict__ T,
                                                                const float* __restrict__ K16l,
                                                                unsigned short* __restrict__ Hi,
                                                                unsigned short* __restrict__ Lo)
{
    __shared__ float tile[64][65];
    int n0 = blockIdx.x * 64, s0 = blockIdx.y * 64;
    int tid = threadIdx.x;
#pragma unroll
    for (int p = 0; p < 4; ++p) {
        int lin = tid + p * 256;
        int r = lin >> 4, c4 = lin & 15;
        float4 v = *(const float4*)&T[(size_t)(n0 + r) * 512 + s0 + c4 * 4];
        tile[r][c4 * 4 + 0] = v.x; tile[r][c4 * 4 + 1] = v.y;
        tile[r][c4 * 4 + 2] = v.z; tile[r][c4 * 4 + 3] = v.w;
    }
    __syncthreads();
    if (n0 == 1984) {
        float o[16];
        if (tid < 64) {
#pragma unroll
            for (int i = 0; i < 16; ++i) {
                float a = 0.0f;
#pragma unroll
                for (int j = 0; j < 16; ++j) a += K16l[i * 16 + j] * tile[48 + j][tid];
                o[i] = a;
            }
        }
        __syncthreads();
        if (tid < 64) {
#pragma unroll
            for (int i = 0; i < 16; ++i) tile[48 + i][tid] = o[i];
        }
        __syncthreads();
    }
#pragma unroll
    for (int p = 0; p < 4; ++p) {
        int lin = tid + p * 256;
        int sl = lin >> 4, j4 = lin & 15;
        unsigned short h[4], l[4];
#pragma unroll
        for (int q = 0; q < 4; ++q) split2(tile[j4 * 4 + q][sl], h[q], l[q]);
        size_t o = (size_t)(s0 + sl) * 2048 + n0 + j4 * 4;
        *(uint2*)&Hi[o] = make_uint2((unsigned)h[0] | ((unsigned)h[1] << 16),
                                     (unsigned)h[2] | ((unsigned)h[3] << 16));
        *(uint2*)&Lo[o] = make_uint2((unsigned)l[0] | ((unsigned)l[1] << 16),
                                     (unsigned)l[2] | ((unsigned)l[3] << 16));
    }
}

// ---------------- chrot (+optional krot) on Tt fp32 -> hi/lo bf16 ----------------
__global__ __launch_bounds__(256) void chrot_t_kernel(const float* __restrict__ C,
                                                      const float* __restrict__ K16l,  // may be null
                                                      const float* __restrict__ in,
                                                      unsigned short* __restrict__ outH,
                                                      unsigned short* __restrict__ outL)
{
    __shared__ float row[2048];
    __shared__ float orow[2048];
    int s = blockIdx.x;
    int tid = threadIdx.x;
    for (int i = tid; i < 512; i += 256) {
        float4 v = *(const float4*)&in[(size_t)s * 2048 + i * 4];
        *(float4*)&row[i * 4] = v;
    }
    __syncthreads();
    int a = tid >> 1, th = (tid & 1) * 8;
    float res[8];
#pragma unroll
    for (int j = 0; j < 8; ++j) res[j] = 0.0f;
    for (int ap = 0; ap < 128; ++ap) {
        float c = C[a * 128 + ap];
#pragma unroll
        for (int j = 0; j < 8; ++j) res[j] += c * row[ap * 16 + th + j];
    }
#pragma unroll
    for (int j = 0; j < 8; ++j) orow[a * 16 + th + j] = res[j];
    __syncthreads();
    if (K16l) {
        float o = 0.0f;
        if (tid < 16) {
#pragma unroll
            for (int j = 0; j < 16; ++j) o += K16l[tid * 16 + j] * orow[2032 + j];
        }
        __syncthreads();
        if (tid < 16) orow[2032 + tid] = o;
        __syncthreads();
    }
    size_t base = (size_t)s * 2048 + (size_t)tid * 8;
    unsigned short h[8], l[8];
#pragma unroll
    for (int q = 0; q < 8; ++q) split2(orow[tid * 8 + q], h[q], l[q]);
    uint4 hv, lv;
    hv.x = (unsigned)h[0] | ((unsigned)h[1] << 16); hv.y = (unsigned)h[2] | ((unsigned)h[3] << 16);
    hv.z = (unsigned)h[4] | ((unsigned)h[5] << 16); hv.w = (unsigned)h[6] | ((unsigned)h[7] << 16);
    lv.x = (unsigned)l[0] | ((unsigned)l[1] << 16); lv.y = (unsigned)l[2] | ((unsigned)l[3] << 16);
    lv.z = (unsigned)l[4] | ((unsigned)l[5] << 16); lv.w = (unsigned)l[6] | ((unsigned)l[7] << 16);
    *(uint4*)&outH[base] = hv;
    *(uint4*)&outL[base] = lv;
}

// ---------------- reduce split-K partials -> fp32 and/or hi/lo (+ parity copy) ----------------
__global__ __launch_bounds__(256) void reduce_hl_kernel(const float* __restrict__ P, int nchunks, int csize,
                                                        float* __restrict__ outF,
                                                        unsigned short* __restrict__ outH,
                                                        unsigned short* __restrict__ outL,
                                                        unsigned short* __restrict__ outPH,
                                                        unsigned short* __restrict__ outPL,
                                                        int rowMask)
{
    int i4 = blockIdx.x * 256 + threadIdx.x;
    size_t base = (size_t)i4 * 4;
    float4 v = *(const float4*)&P[base];
    for (int c = 1; c < nchunks; ++c) {
        float4 u = *(const float4*)&P[(size_t)c * csize + base];
        v.x += u.x; v.y += u.y; v.z += u.z; v.w += u.w;
    }
    if (outF) *(float4*)&outF[base] = v;
    float f[4] = {v.x, v.y, v.z, v.w};
    unsigned short h[4], l[4];
#pragma unroll
    for (int q = 0; q < 4; ++q) split2(f[q], h[q], l[q]);
    if (outH) {
        *(uint2*)&outH[base] = make_uint2((unsigned)h[0] | ((unsigned)h[1] << 16),
                                          (unsigned)h[2] | ((unsigned)h[3] << 16));
        *(uint2*)&outL[base] = make_uint2((unsigned)l[0] | ((unsigned)l[1] << 16),
                                          (unsigned)l[2] | ((unsigned)l[3] << 16));
    }
    if (outPH) {
        unsigned short ph[4], pl[4];
#pragma unroll
        for (int q = 0; q < 4; ++q) {
            int n = (int)((base + q) & (size_t)rowMask);
            unsigned flip = ((unsigned)(__popc(n) & 1)) << 15;
            ph[q] = h[q] ^ (unsigned short)flip;
            pl[q] = l[q] ^ (unsigned short)flip;
        }
        *(uint2*)&outPH[base] = make_uint2((unsigned)ph[0] | ((unsigned)ph[1] << 16),
                                           (unsigned)ph[2] | ((unsigned)ph[3] << 16));
        *(uint2*)&outPL[base] = make_uint2((unsigned)pl[0] | ((unsigned)pl[1] << 16),
                                           (unsigned)pl[2] | ((unsigned)pl[3] << 16));
    }
}

// ---------------- hi/lo split bf16 MFMA GEMM (round-7 structure + setprio) ----------------
// C[M,N] = A[M,K]@B^T[N,K]; 64x64 tile, 256 threads, 4-wave k-split, K_STEP=64,
// double-buffered 64KB LDS (2 blocks/CU), prefetch-before-compute pipeline.
// EPI 3: fp32 transposed partials into Cout + kc*M*N (split-K via grid.z)
// EPI 4: fused row-dot: atomicAdd(accOut[bm*64+row], sum_col Ytile*X)
template<int EPI>
__global__ __launch_bounds__(256) void gemm_hl_kernel(
    const unsigned short* __restrict__ Ahi, const unsigned short* __restrict__ Alo, int ldA,
    const unsigned short* __restrict__ Bhi, const unsigned short* __restrict__ Blo, int ldB,
    float* __restrict__ Cout,
    const float* __restrict__ Xf, float* __restrict__ accOut,
    int M, int N, int Kchunk)
{
    __shared__ __align__(16) char smem[65536];  // 2 buffers x (Ah|Al|Bh|Bl, 8KB each)
    const int tid = threadIdx.x;
    const int lane = tid & 63;
    const int w = tid >> 6;
    const int bm = blockIdx.x, bn = blockIdx.y, kc = blockIdx.z;
    const int kbase = kc * Kchunk;

    f32x16 acc[2][2];
#pragma unroll
    for (int i = 0; i < 2; ++i)
#pragma unroll
        for (int j = 0; j < 2; ++j)
#pragma unroll
            for (int q = 0; q < 16; ++q) acc[i][j][q] = 0.0f;

    const int col = lane & 31;
    const int hi = lane >> 5;
    const int k16 = w * 16;
    int aaddr[2];
#pragma unroll
    for (int ms = 0; ms < 2; ++ms) {
        int row = ms * 32 + col;
        int cb = (k16 + hi * 8) * 2;
        aaddr[ms] = row * 128 + (cb ^ ((row & 7) << 4));
    }
    int srow[2], sge[2], sdst[2];
#pragma unroll
    for (int p = 0; p < 2; ++p) {
        int slot = p * 4096 + tid * 16;
        int r = slot >> 7;
        int pc = slot & 127;
        int lc = pc ^ ((r & 7) << 4);
        srow[p] = r;
        sge[p] = lc >> 1;
        sdst[p] = p * 4096 + w * 1024;
    }

#define STAGE(BUF, KG)                                                                     \
    {                                                                                      \
        _Pragma("unroll")                                                                  \
        for (int p = 0; p < 2; ++p) {                                                      \
            int ge = (KG) + sge[p];                                                        \
            async_copy16(Ahi + (size_t)(bm * 64 + srow[p]) * ldA + ge,                     \
                         &smem[(BUF) * 32768 + 0 + sdst[p]]);                              \
            async_copy16(Alo + (size_t)(bm * 64 + srow[p]) * ldA + ge,                     \
                         &smem[(BUF) * 32768 + 8192 + sdst[p]]);                           \
            async_copy16(Bhi + (size_t)(bn * 64 + srow[p]) * ldB + ge,                     \
                         &smem[(BUF) * 32768 + 16384 + sdst[p]]);                          \
            async_copy16(Blo + (size_t)(bn * 64 + srow[p]) * ldB + ge,                     \
                         &smem[(BUF) * 32768 + 24576 + sdst[p]]);                          \
        }                                                                                  \
    }

    const int nsteps = Kchunk >> 6;
    STAGE(0, kbase);
    asm volatile("s_waitcnt vmcnt(0)" ::: "memory");
    __builtin_amdgcn_s_barrier();
    __builtin_amdgcn_sched_barrier(0);

    int cur = 0;
    for (int kt = 0; kt < nsteps; ++kt) {
        const bool havenext = (kt + 1 < nsteps);
        if (havenext) STAGE(cur ^ 1, kbase + ((kt + 1) << 6));   // prefetch flies over compute
        __builtin_amdgcn_sched_barrier(0);
        const char* base = &smem[cur * 32768];
        bf16x8 ah[2], al[2], bh[2], bl[2];
#pragma unroll
        for (int ms = 0; ms < 2; ++ms) {
            ah[ms] = *(const bf16x8*)(base + 0 + aaddr[ms]);
            al[ms] = *(const bf16x8*)(base + 8192 + aaddr[ms]);
        }
#pragma unroll
        for (int ns = 0; ns < 2; ++ns) {
            bh[ns] = *(const bf16x8*)(base + 16384 + aaddr[ns]);
            bl[ns] = *(const bf16x8*)(base + 24576 + aaddr[ns]);
        }
        __builtin_amdgcn_s_setprio(1);
#pragma unroll
        for (int ms = 0; ms < 2; ++ms)
#pragma unroll
            for (int ns = 0; ns < 2; ++ns) {
                acc[ms][ns] = __builtin_amdgcn_mfma_f32_32x32x16_bf16(ah[ms], bh[ns], acc[ms][ns], 0, 0, 0);
                acc[ms][ns] = __builtin_amdgcn_mfma_f32_32x32x16_bf16(ah[ms], bl[ns], acc[ms][ns], 0, 0, 0);
                acc[ms][ns] = __builtin_amdgcn_mfma_f32_32x32x16_bf16(al[ms], bh[ns], acc[ms][ns], 0, 0, 0);
            }
        __builtin_amdgcn_s_setprio(0);
        __builtin_amdgcn_sched_barrier(0);
        if (havenext) {
            asm volatile("s_waitcnt vmcnt(0)" ::: "memory");     // prefetch landed (flew over MFMAs)
        }
        __builtin_amdgcn_s_barrier();
        __builtin_amdgcn_sched_barrier(0);
        cur ^= 1;
    }
#undef STAGE

    // 4-wave k-split tree reduction through LDS
    float* red = (float*)smem;
    if (w >= 2) {
        float* dst = red + (w - 2) * 4096;
#pragma unroll
        for (int ms = 0; ms < 2; ++ms)
#pragma unroll
            for (int ns = 0; ns < 2; ++ns)
#pragma unroll
                for (int r = 0; r < 16; ++r) {
                    int rowr = (r & 3) + 8 * (r >> 2) + 4 * hi;
                    dst[(ms * 32 + rowr) * 64 + ns * 32 + col] = acc[ms][ns][r];
                }
    }
    __syncthreads();
    if (w < 2) {
        float* src = red + w * 4096;
#pragma unroll
        for (int ms = 0; ms < 2; ++ms)
#pragma unroll
            for (int ns = 0; ns < 2; ++ns)
#pragma unroll
                for (int r = 0; r < 16; ++r) {
                    int rowr = (r & 3) + 8 * (r >> 2) + 4 * hi;
                    acc[ms][ns][r] += src[(ms * 32 + rowr) * 64 + ns * 32 + col];
                }
    }
    __syncthreads();
    if (w == 1) {
#pragma unroll
        for (int ms = 0; ms < 2; ++ms)
#pragma unroll
            for (int ns = 0; ns < 2; ++ns)
#pragma unroll
                for (int r = 0; r < 16; ++r) {
                    int rowr = (r & 3) + 8 * (r >> 2) + 4 * hi;
                    red[(ms * 32 + rowr) * 64 + ns * 32 + col] = acc[ms][ns][r];
                }
    }
    __syncthreads();
    if (w == 0) {
#pragma unroll
        for (int ms = 0; ms < 2; ++ms)
#pragma unroll
            for (int ns = 0; ns < 2; ++ns)
#pragma unroll
                for (int r = 0; r < 16; ++r) {
                    int rowr = (r & 3) + 8 * (r >> 2) + 4 * hi;
                    acc[ms][ns][r] += red[(ms * 32 + rowr) * 64 + ns * 32 + col];
                }
        if (EPI == 3) {
            float* dstC = Cout + (size_t)kc * M * N;
#pragma unroll
            for (int ms = 0; ms < 2; ++ms)
#pragma unroll
                for (int ns = 0; ns < 2; ++ns)
#pragma unroll
                    for (int g = 0; g < 4; ++g) {
                        int rowt = ms * 32 + 8 * g + 4 * hi;
                        float4 v = make_float4(acc[ms][ns][4 * g + 0], acc[ms][ns][4 * g + 1],
                                               acc[ms][ns][4 * g + 2], acc[ms][ns][4 * g + 3]);
                        *(float4*)&dstC[(size_t)(bn * 64 + ns * 32 + col) * M + bm * 64 + rowt] = v;
                    }
        }
        if (EPI == 4) {
#pragma unroll
            for (int ms = 0; ms < 2; ++ms)
#pragma unroll
                for (int ns = 0; ns < 2; ++ns)
#pragma unroll
                    for (int r = 0; r < 16; ++r) {
                        int rowr = (r & 3) + 8 * (r >> 2) + 4 * hi;
                        red[(ms * 32 + rowr) * 64 + ns * 32 + col] = acc[ms][ns][r];
                    }
        }
    }
    if (EPI == 4) {
        __syncthreads();
        int row = tid >> 2, q = tid & 3;
        const float* xrow = Xf + (size_t)(bm * 64 + row) * 512 + bn * 64 + q * 16;
        const float* yr = &red[row * 64 + q * 16];
        float s = 0.0f;
#pragma unroll
        for (int j4 = 0; j4 < 4; ++j4) {
            float4 x = *(const float4*)&xrow[j4 * 4];
            s += x.x * yr[j4 * 4 + 0] + x.y * yr[j4 * 4 + 1] +
                 x.z * yr[j4 * 4 + 2] + x.w * yr[j4 * 4 + 3];
        }
        s += __shfl_xor(s, 1, 64);
        s += __shfl_xor(s, 2, 64);
        if (q == 0) atomicAdd(&accOut[bm * 64 + row], s);
    }
}

// ---------------- out[b] = acc[b] / (4*mag[b]) ----------------
__global__ __launch_bounds__(256) void divide_kernel(const float* __restrict__ acc,
                                                     const float* __restrict__ mag,
                                                     float* __restrict__ out)
{
    int b = blockIdx.x * 256 + threadIdx.x;
    out[b] = acc[b] / (4.0f * mag[b]);
}

// ================= launcher =================
extern "C" void kernel_launch(void* const* d_in, const int* in_sizes, int n_in,
                              void* d_out, int out_size, void* d_ws, size_t ws_size,
                              hipStream_t stream)
{
    const float* X = (const float*)d_in[0];
    const float* chang = (const float*)d_in[1];
    const float* kang = (const float*)d_in[2];
    const float* cent = (const float*)d_in[3];
    const float* kent = (const float*)d_in[4];
    float* out = (float*)d_out;

    size_t off = 0;
    auto alloc = [&](size_t bytes) -> char* {
        char* p = (char*)d_ws + off;
        off += (bytes + 255) & ~(size_t)255;
        return p;
    };
    float* bufT = (float*)alloc(2048 * 512 * 4);            // T0 fp32
    float* TtA = (float*)alloc(512 * 2048 * 4);             // fp32 pre-chrot
    float* Pa = (float*)alloc(8 * 512 * 512 * 4);           // split-K partials (8MB)
    float* C128 = (float*)alloc(2 * 128 * 128 * 4);
    float* K16 = (float*)alloc(2 * 16 * 16 * 4);
    float* mag = (float*)alloc(8192 * 4);
    float* acc = (float*)alloc(8192 * 4);
    unsigned short* T0hi = (unsigned short*)alloc(512 * 2048 * 2);
    unsigned short* T0lo = (unsigned short*)alloc(512 * 2048 * 2);
    unsigned short* T1hi = (unsigned short*)alloc(512 * 2048 * 2);
    unsigned short* T1lo = (unsigned short*)alloc(512 * 2048 * 2);
    unsigned short* TPhi = (unsigned short*)alloc(512 * 2048 * 2);
    unsigned short* TPlo = (unsigned short*)alloc(512 * 2048 * 2);
    unsigned short* Ghi = (unsigned short*)alloc(512 * 512 * 2);
    unsigned short* Glo = (unsigned short*)alloc(512 * 512 * 2);
    unsigned short* Xhi = (unsigned short*)alloc(8192 * 512 * 2);
    unsigned short* Xlo = (unsigned short*)alloc(8192 * 512 * 2);
    unsigned short* keHi = (unsigned short*)alloc(2048 * 2048 * 2);
    unsigned short* keLo = (unsigned short*)alloc(2048 * 2048 * 2);
    unsigned short* cehi = (unsigned short*)alloc(2048 * 2048 * 2);
    unsigned short* celo = (unsigned short*)alloc(2048 * 2048 * 2);
    (void)ws_size;

    prep_kernel<<<6208, 256, 0, stream>>>(X, chang, kang, cent, kent,
                                          keHi, keLo, cehi, celo,
                                          Xhi, Xlo, mag, acc, bufT, C128, K16);
    transpose_convert_kernel<<<dim3(32, 8), 256, 0, stream>>>(bufT, K16 + 256, T0hi, T0lo); // +kr1

    const int CS = 2048 * 512;   // chain partial chunk size (floats)
    // G1: kent @ T -> partials -> hi/lo
    gemm_hl_kernel<3><<<dim3(32, 8, 2), 256, 0, stream>>>(
        keHi, keLo, 2048, T0hi, T0lo, 2048, Pa, nullptr, nullptr, 2048, 512, 1024);
    reduce_hl_kernel<<<1024, 256, 0, stream>>>(Pa, 2, CS, nullptr, T1hi, T1lo, nullptr, nullptr, 0);
    // G2: cent @ T -> partials -> fp32 (chrot next)
    gemm_hl_kernel<3><<<dim3(32, 8, 2), 256, 0, stream>>>(
        cehi, celo, 2048, T1hi, T1lo, 2048, Pa, nullptr, nullptr, 2048, 512, 1024);
    reduce_hl_kernel<<<1024, 256, 0, stream>>>(Pa, 2, CS, TtA, nullptr, nullptr, nullptr, nullptr, 0);
    chrot_t_kernel<<<512, 256, 0, stream>>>(C128 + 16384, K16, TtA, T0hi, T0lo);   // ch1 + kr0
    // G3: kent @ T
    gemm_hl_kernel<3><<<dim3(32, 8, 2), 256, 0, stream>>>(
        keHi, keLo, 2048, T0hi, T0lo, 2048, Pa, nullptr, nullptr, 2048, 512, 1024);
    reduce_hl_kernel<<<1024, 256, 0, stream>>>(Pa, 2, CS, nullptr, T1hi, T1lo, nullptr, nullptr, 0);
    // G4: cent @ T -> fp32 (chrot next)
    gemm_hl_kernel<3><<<dim3(32, 8, 2), 256, 0, stream>>>(
        cehi, celo, 2048, T1hi, T1lo, 2048, Pa, nullptr, nullptr, 2048, 512, 1024);
    reduce_hl_kernel<<<1024, 256, 0, stream>>>(Pa, 2, CS, TtA, nullptr, nullptr, nullptr, nullptr, 0);
    chrot_t_kernel<<<512, 256, 0, stream>>>(C128, nullptr, TtA, T0hi, T0lo);        // ch0
    // G5: cent @ T -> hi/lo + parity copy
    gemm_hl_kernel<3><<<dim3(32, 8, 2), 256, 0, stream>>>(
        cehi, celo, 2048, T0hi, T0lo, 2048, Pa, nullptr, nullptr, 2048, 512, 1024);
    reduce_hl_kernel<<<1024, 256, 0, stream>>>(Pa, 2, CS, nullptr, T1hi, T1lo, TPhi, TPlo, 2047);
    // ghat: split-K=8 -> reduce -> Ghi/Glo
    gemm_hl_kernel<3><<<dim3(8, 8, 8), 256, 0, stream>>>(
        T1hi, T1lo, 2048, TPhi, TPlo, 2048, Pa, nullptr, nullptr, 512, 512, 256);
    reduce_hl_kernel<<<256, 256, 0, stream>>>(Pa, 8, 512 * 512, nullptr, Ghi, Glo, nullptr, nullptr, 0);
    // final: fused X@G^T row-dot -> acc
    gemm_hl_kernel<4><<<dim3(128, 8, 1), 256, 0, stream>>>(
        Xhi, Xlo, 512, Ghi, Glo, 512, nullptr, X, acc, 8192, 512, 512);
    divide_kernel<<<32, 256, 0, stream>>>(acc, mag, out);
}

// Round 10
// 197.754 us; speedup vs baseline: 1.0704x; 1.0380x over previous
//
#include <hip/hip_runtime.h>
#include <math.h>

#ifndef M_PI
#define M_PI 3.14159265358979323846
#endif

// out[b] = (x_b^T Ghat x_b) / (4 * mag_b),  mag = sqrt(sum x^2)+1e-7
// Ghat = (M E)^T diag(parity) (M E),  chain applied right-to-left to E,
// T kept transposed as Tt[512][2048]. Dense products: bf16 hi/lo split MFMA
// (3 products, fp32 accum), split-K=2 (2 blocks/CU co-residency), setprio
// around MFMA cluster. Glue fused: chrot consumes split-K partial PAIRS;
// final GEMM scales by 1/(4 mag) and accumulates straight into d_out.

typedef __attribute__((ext_vector_type(8))) short bf16x8;
typedef __attribute__((ext_vector_type(16))) float f32x16;

// ---------------- helpers ----------------
__device__ __forceinline__ unsigned short bf16_rne(float f) {
    unsigned u = __float_as_uint(f);
    unsigned r = u + 0x7FFFu + ((u >> 16) & 1u);
    return (unsigned short)(r >> 16);
}
__device__ __forceinline__ void split2(float f, unsigned short& h, unsigned short& l) {
    h = bf16_rne(f);
    float fh = __uint_as_float(((unsigned)h) << 16);
    l = bf16_rne(f - fh);
}
__device__ __forceinline__ void async_copy16(const void* gsrc, void* ldst) {
    __builtin_amdgcn_global_load_lds(
        (const __attribute__((address_space(1))) unsigned int*)gsrc,
        (__attribute__((address_space(3))) unsigned int*)ldst,
        16, 0, 0);
}

// ---------------- merged prep ----------------
// blocks [0,2048):    kent row -> keHi/keLo + collapse row into bufT
// blocks [2048,4096): cent row -> cehi/celo
// blocks [4096,6144): X 4 rows/block -> Xhi/Xlo + mag + zero out
// blocks [6144,6208): rotation matrices C128 (2x128x128), K16 (2x16x16)
__global__ __launch_bounds__(256) void prep_kernel(
    const float* __restrict__ X,
    const float* __restrict__ ch_ang, const float* __restrict__ k_ang,
    const float* __restrict__ cent, const float* __restrict__ kent,
    unsigned short* __restrict__ keHi, unsigned short* __restrict__ keLo,
    unsigned short* __restrict__ cehi, unsigned short* __restrict__ celo,
    unsigned short* __restrict__ Xhi, unsigned short* __restrict__ Xlo,
    float* __restrict__ mag, float* __restrict__ outZ,
    float* __restrict__ bufT,
    float* __restrict__ C128, float* __restrict__ K16)
{
    __shared__ float row[2048];
    int blk = blockIdx.x;
    int tid = threadIdx.x;

    if (blk < 4096) {
        int n = blk & 2047;
        bool isk = (blk < 2048);
        const float* src = isk ? kent : cent;
        unsigned short* oh = isk ? keHi : cehi;
        unsigned short* ol = isk ? keLo : celo;
        size_t base = (size_t)n * 2048 + (size_t)tid * 8;
        float4 v0 = *(const float4*)&src[base];
        float4 v1 = *(const float4*)&src[base + 4];
        float f[8] = {v0.x, v0.y, v0.z, v0.w, v1.x, v1.y, v1.z, v1.w};
        if (isk) {
            *(float4*)&row[tid * 8] = v0;
            *(float4*)&row[tid * 8 + 4] = v1;
        }
        unsigned short h[8], l[8];
#pragma unroll
        for (int q = 0; q < 8; ++q) split2(f[q], h[q], l[q]);
        uint4 hv, lv;
        hv.x = (unsigned)h[0] | ((unsigned)h[1] << 16); hv.y = (unsigned)h[2] | ((unsigned)h[3] << 16);
        hv.z = (unsigned)h[4] | ((unsigned)h[5] << 16); hv.w = (unsigned)h[6] | ((unsigned)h[7] << 16);
        lv.x = (unsigned)l[0] | ((unsigned)l[1] << 16); lv.y = (unsigned)l[2] | ((unsigned)l[3] << 16);
        lv.z = (unsigned)l[4] | ((unsigned)l[5] << 16); lv.w = (unsigned)l[6] | ((unsigned)l[7] << 16);
        *(uint4*)&oh[base] = hv;
        *(uint4*)&ol[base] = lv;
        if (isk) {
            __syncthreads();
#pragma unroll
            for (int i = 0; i < 2; ++i) {
                int s = tid + i * 256;
                float a = 0.0f;
#pragma unroll
                for (int dj = 0; dj < 2; ++dj) {
                    int j = 2 * s + dj;
                    int m0 = ((j >> 4) << 5) | (j & 15);
                    a += row[m0] + row[m0 + 16];
                }
                bufT[(size_t)n * 512 + s] = a;
            }
        }
    } else if (blk < 6144) {
        int w = tid >> 6, lane = tid & 63;
        int b = (blk - 4096) * 4 + w;
        size_t base = (size_t)b * 512 + (size_t)lane * 8;
        float4 v0 = *(const float4*)&X[base];
        float4 v1 = *(const float4*)&X[base + 4];
        float f[8] = {v0.x, v0.y, v0.z, v0.w, v1.x, v1.y, v1.z, v1.w};
        unsigned short h[8], l[8];
#pragma unroll
        for (int q = 0; q < 8; ++q) split2(f[q], h[q], l[q]);
        uint4 hv, lv;
        hv.x = (unsigned)h[0] | ((unsigned)h[1] << 16); hv.y = (unsigned)h[2] | ((unsigned)h[3] << 16);
        hv.z = (unsigned)h[4] | ((unsigned)h[5] << 16); hv.w = (unsigned)h[6] | ((unsigned)h[7] << 16);
        lv.x = (unsigned)l[0] | ((unsigned)l[1] << 16); lv.y = (unsigned)l[2] | ((unsigned)l[3] << 16);
        lv.z = (unsigned)l[4] | ((unsigned)l[5] << 16); lv.w = (unsigned)l[6] | ((unsigned)l[7] << 16);
        *(uint4*)&Xhi[base] = hv;
        *(uint4*)&Xlo[base] = lv;
        float ss = 0.0f;
#pragma unroll
        for (int q = 0; q < 8; ++q) ss += f[q] * f[q];
#pragma unroll
        for (int off = 32; off; off >>= 1) ss += __shfl_xor(ss, off, 64);
        if (lane == 0) {
            mag[b] = sqrtf(ss) + 1e-7f;
            outZ[b] = 0.0f;
        }
    } else {
        int t = (blk - 6144) * 256 + tid;
        int stride = 64 * 256;
        for (int idx = t; idx < 2 * 128 * 128; idx += stride) {
            int l = idx >> 14;
            int rem = idx & 16383;
            int a = rem >> 7, b = rem & 127;
            float p = 1.0f;
#pragma unroll
            for (int q = 0; q < 7; ++q) {
                float half = ch_ang[l * 7 + q] * (float)M_PI;
                float c = cosf(half), s = sinf(half);
                int ia = (a >> (6 - q)) & 1;
                int ib = (b >> (6 - q)) & 1;
                float e = ia ? (ib ? c : s) : (ib ? -s : c);
                p *= e;
            }
            C128[idx] = p;
        }
        for (int idx = t; idx < 2 * 16 * 16; idx += stride) {
            int l = idx >> 8;
            int rem = idx & 255;
            int a = rem >> 4, b = rem & 15;
            float p = 1.0f;
#pragma unroll
            for (int q = 0; q < 4; ++q) {
                float half = k_ang[l * 4 + q] * 0.5f;
                float c = cosf(half), s = sinf(half);
                int ia = (a >> (3 - q)) & 1;
                int ib = (b >> (3 - q)) & 1;
                float e = ia ? (ib ? c : s) : (ib ? -s : c);
                p *= e;
            }
            K16[idx] = p;
        }
    }
}

// ---------------- transpose T[2048][512] -> Tt hi/lo [512][2048], kr1 fused ----------------
__global__ __launch_bounds__(256) void transpose_convert_kernel(const float* __restrict__ T,
                                                                const float* __restrict__ K16l,
                                                                unsigned short* __restrict__ Hi,
                                                                unsigned short* __restrict__ Lo)
{
    __shared__ float tile[64][65];
    int n0 = blockIdx.x * 64, s0 = blockIdx.y * 64;
    int tid = threadIdx.x;
#pragma unroll
    for (int p = 0; p < 4; ++p) {
        int lin = tid + p * 256;
        int r = lin >> 4, c4 = lin & 15;
        float4 v = *(const float4*)&T[(size_t)(n0 + r) * 512 + s0 + c4 * 4];
        tile[r][c4 * 4 + 0] = v.x; tile[r][c4 * 4 + 1] = v.y;
        tile[r][c4 * 4 + 2] = v.z; tile[r][c4 * 4 + 3] = v.w;
    }
    __syncthreads();
    if (n0 == 1984) {
        float o[16];
        if (tid < 64) {
#pragma unroll
            for (int i = 0; i < 16; ++i) {
                float a = 0.0f;
#pragma unroll
                for (int j = 0; j < 16; ++j) a += K16l[i * 16 + j] * tile[48 + j][tid];
                o[i] = a;
            }
        }
        __syncthreads();
        if (tid < 64) {
#pragma unroll
            for (int i = 0; i < 16; ++i) tile[48 + i][tid] = o[i];
        }
        __syncthreads();
    }
#pragma unroll
    for (int p = 0; p < 4; ++p) {
        int lin = tid + p * 256;
        int sl = lin >> 4, j4 = lin & 15;
        unsigned short h[4], l[4];
#pragma unroll
        for (int q = 0; q < 4; ++q) split2(tile[j4 * 4 + q][sl], h[q], l[q]);
        size_t o = (size_t)(s0 + sl) * 2048 + n0 + j4 * 4;
        *(uint2*)&Hi[o] = make_uint2((unsigned)h[0] | ((unsigned)h[1] << 16),
                                     (unsigned)h[2] | ((unsigned)h[3] << 16));
        *(uint2*)&Lo[o] = make_uint2((unsigned)l[0] | ((unsigned)l[1] << 16),
                                     (unsigned)l[2] | ((unsigned)l[3] << 16));
    }
}

// ---------------- chrot (+optional krot) on split-K partial PAIR -> hi/lo bf16 ----------------
__global__ __launch_bounds__(256) void chrot_t_kernel(const float* __restrict__ C,
                                                      const float* __restrict__ K16l,  // may be null
                                                      const float* __restrict__ in0,
                                                      const float* __restrict__ in1,
                                                      unsigned short* __restrict__ outH,
                                                      unsigned short* __restrict__ outL)
{
    __shared__ float row[2048];
    __shared__ float orow[2048];
    int s = blockIdx.x;
    int tid = threadIdx.x;
    for (int i = tid; i < 512; i += 256) {
        float4 a = *(const float4*)&in0[(size_t)s * 2048 + i * 4];
        float4 b = *(const float4*)&in1[(size_t)s * 2048 + i * 4];
        a.x += b.x; a.y += b.y; a.z += b.z; a.w += b.w;
        *(float4*)&row[i * 4] = a;
    }
    __syncthreads();
    int a = tid >> 1, th = (tid & 1) * 8;
    float res[8];
#pragma unroll
    for (int j = 0; j < 8; ++j) res[j] = 0.0f;
    for (int ap = 0; ap < 128; ++ap) {
        float c = C[a * 128 + ap];
#pragma unroll
        for (int j = 0; j < 8; ++j) res[j] += c * row[ap * 16 + th + j];
    }
#pragma unroll
    for (int j = 0; j < 8; ++j) orow[a * 16 + th + j] = res[j];
    __syncthreads();
    if (K16l) {
        float o = 0.0f;
        if (tid < 16) {
#pragma unroll
            for (int j = 0; j < 16; ++j) o += K16l[tid * 16 + j] * orow[2032 + j];
        }
        __syncthreads();
        if (tid < 16) orow[2032 + tid] = o;
        __syncthreads();
    }
    size_t base = (size_t)s * 2048 + (size_t)tid * 8;
    unsigned short h[8], l[8];
#pragma unroll
    for (int q = 0; q < 8; ++q) split2(orow[tid * 8 + q], h[q], l[q]);
    uint4 hv, lv;
    hv.x = (unsigned)h[0] | ((unsigned)h[1] << 16); hv.y = (unsigned)h[2] | ((unsigned)h[3] << 16);
    hv.z = (unsigned)h[4] | ((unsigned)h[5] << 16); hv.w = (unsigned)h[6] | ((unsigned)h[7] << 16);
    lv.x = (unsigned)l[0] | ((unsigned)l[1] << 16); lv.y = (unsigned)l[2] | ((unsigned)l[3] << 16);
    lv.z = (unsigned)l[4] | ((unsigned)l[5] << 16); lv.w = (unsigned)l[6] | ((unsigned)l[7] << 16);
    *(uint4*)&outH[base] = hv;
    *(uint4*)&outL[base] = lv;
}

// ---------------- reduce split-K partials -> hi/lo (+ optional parity copy) ----------------
__global__ __launch_bounds__(256) void reduce_hl_kernel(const float* __restrict__ P, int nchunks, int csize,
                                                        unsigned short* __restrict__ outH,
                                                        unsigned short* __restrict__ outL,
                                                        unsigned short* __restrict__ outPH,
                                                        unsigned short* __restrict__ outPL,
                                                        int rowMask)
{
    int i4 = blockIdx.x * 256 + threadIdx.x;
    size_t base = (size_t)i4 * 4;
    float4 v = *(const float4*)&P[base];
    for (int c = 1; c < nchunks; ++c) {
        float4 u = *(const float4*)&P[(size_t)c * csize + base];
        v.x += u.x; v.y += u.y; v.z += u.z; v.w += u.w;
    }
    float f[4] = {v.x, v.y, v.z, v.w};
    unsigned short h[4], l[4];
#pragma unroll
    for (int q = 0; q < 4; ++q) split2(f[q], h[q], l[q]);
    *(uint2*)&outH[base] = make_uint2((unsigned)h[0] | ((unsigned)h[1] << 16),
                                      (unsigned)h[2] | ((unsigned)h[3] << 16));
    *(uint2*)&outL[base] = make_uint2((unsigned)l[0] | ((unsigned)l[1] << 16),
                                      (unsigned)l[2] | ((unsigned)l[3] << 16));
    if (outPH) {
        unsigned short ph[4], pl[4];
#pragma unroll
        for (int q = 0; q < 4; ++q) {
            int n = (int)((base + q) & (size_t)rowMask);
            unsigned flip = ((unsigned)(__popc(n) & 1)) << 15;
            ph[q] = h[q] ^ (unsigned short)flip;
            pl[q] = l[q] ^ (unsigned short)flip;
        }
        *(uint2*)&outPH[base] = make_uint2((unsigned)ph[0] | ((unsigned)ph[1] << 16),
                                           (unsigned)ph[2] | ((unsigned)ph[3] << 16));
        *(uint2*)&outPL[base] = make_uint2((unsigned)pl[0] | ((unsigned)pl[1] << 16),
                                           (unsigned)pl[2] | ((unsigned)pl[3] << 16));
    }
}

// ---------------- hi/lo split bf16 MFMA GEMM ----------------
// C[M,N] = A[M,K]@B^T[N,K]; 64x64 tile, 256 threads, 4-wave k-split, K_STEP=64,
// double-buffered 64KB LDS (2 blocks/CU), prefetch-before-compute pipeline,
// setprio(1) around MFMA cluster.
// EPI 3: fp32 transposed partials into Cout + kc*M*N (split-K via grid.z)
// EPI 4: fused row-dot scaled by 1/(4*mag): atomicAdd into out directly
template<int EPI>
__global__ __launch_bounds__(256) void gemm_hl_kernel(
    const unsigned short* __restrict__ Ahi, const unsigned short* __restrict__ Alo, int ldA,
    const unsigned short* __restrict__ Bhi, const unsigned short* __restrict__ Blo, int ldB,
    float* __restrict__ Cout,
    const float* __restrict__ Xf, const float* __restrict__ magv,
    float* __restrict__ accOut,
    int M, int N, int Kchunk)
{
    __shared__ __align__(16) char smem[65536];  // 2 buffers x (Ah|Al|Bh|Bl, 8KB each)
    const int tid = threadIdx.x;
    const int lane = tid & 63;
    const int w = tid >> 6;
    const int bm = blockIdx.x, bn = blockIdx.y, kc = blockIdx.z;
    const int kbase = kc * Kchunk;

    f32x16 acc[2][2];
#pragma unroll
    for (int i = 0; i < 2; ++i)
#pragma unroll
        for (int j = 0; j < 2; ++j)
#pragma unroll
            for (int q = 0; q < 16; ++q) acc[i][j][q] = 0.0f;

    const int col = lane & 31;
    const int hi = lane >> 5;
    const int k16 = w * 16;
    int aaddr[2];
#pragma unroll
    for (int ms = 0; ms < 2; ++ms) {
        int row = ms * 32 + col;
        int cb = (k16 + hi * 8) * 2;
        aaddr[ms] = row * 128 + (cb ^ ((row & 7) << 4));
    }
    int srow[2], sge[2], sdst[2];
#pragma unroll
    for (int p = 0; p < 2; ++p) {
        int slot = p * 4096 + tid * 16;
        int r = slot >> 7;
        int pc = slot & 127;
        int lc = pc ^ ((r & 7) << 4);
        srow[p] = r;
        sge[p] = lc >> 1;
        sdst[p] = p * 4096 + w * 1024;
    }

#define STAGE(BUF, KG)                                                                     \
    {                                                                                      \
        _Pragma("unroll")                                                                  \
        for (int p = 0; p < 2; ++p) {                                                      \
            int ge = (KG) + sge[p];                                                        \
            async_copy16(Ahi + (size_t)(bm * 64 + srow[p]) * ldA + ge,                     \
                         &smem[(BUF) * 32768 + 0 + sdst[p]]);                              \
            async_copy16(Alo + (size_t)(bm * 64 + srow[p]) * ldA + ge,                     \
                         &smem[(BUF) * 32768 + 8192 + sdst[p]]);                           \
            async_copy16(Bhi + (size_t)(bn * 64 + srow[p]) * ldB + ge,                     \
                         &smem[(BUF) * 32768 + 16384 + sdst[p]]);                          \
            async_copy16(Blo + (size_t)(bn * 64 + srow[p]) * ldB + ge,                     \
                         &smem[(BUF) * 32768 + 24576 + sdst[p]]);                          \
        }                                                                                  \
    }

    const int nsteps = Kchunk >> 6;
    STAGE(0, kbase);
    asm volatile("s_waitcnt vmcnt(0)" ::: "memory");
    __builtin_amdgcn_s_barrier();
    __builtin_amdgcn_sched_barrier(0);

    int cur = 0;
    for (int kt = 0; kt < nsteps; ++kt) {
        const bool havenext = (kt + 1 < nsteps);
        if (havenext) STAGE(cur ^ 1, kbase + ((kt + 1) << 6));   // prefetch flies over compute
        __builtin_amdgcn_sched_barrier(0);
        const char* base = &smem[cur * 32768];
        bf16x8 ah[2], al[2], bh[2], bl[2];
#pragma unroll
        for (int ms = 0; ms < 2; ++ms) {
            ah[ms] = *(const bf16x8*)(base + 0 + aaddr[ms]);
            al[ms] = *(const bf16x8*)(base + 8192 + aaddr[ms]);
        }
#pragma unroll
        for (int ns = 0; ns < 2; ++ns) {
            bh[ns] = *(const bf16x8*)(base + 16384 + aaddr[ns]);
            bl[ns] = *(const bf16x8*)(base + 24576 + aaddr[ns]);
        }
        __builtin_amdgcn_s_setprio(1);
#pragma unroll
        for (int ms = 0; ms < 2; ++ms)
#pragma unroll
            for (int ns = 0; ns < 2; ++ns) {
                acc[ms][ns] = __builtin_amdgcn_mfma_f32_32x32x16_bf16(ah[ms], bh[ns], acc[ms][ns], 0, 0, 0);
                acc[ms][ns] = __builtin_amdgcn_mfma_f32_32x32x16_bf16(ah[ms], bl[ns], acc[ms][ns], 0, 0, 0);
                acc[ms][ns] = __builtin_amdgcn_mfma_f32_32x32x16_bf16(al[ms], bh[ns], acc[ms][ns], 0, 0, 0);
            }
        __builtin_amdgcn_s_setprio(0);
        __builtin_amdgcn_sched_barrier(0);
        if (havenext) {
            asm volatile("s_waitcnt vmcnt(0)" ::: "memory");     // prefetch landed (flew over MFMAs)
        }
        __builtin_amdgcn_s_barrier();
        __builtin_amdgcn_sched_barrier(0);
        cur ^= 1;
    }
#undef STAGE

    // 4-wave k-split tree reduction through LDS
    float* red = (float*)smem;
    if (w >= 2) {
        float* dst = red + (w - 2) * 4096;
#pragma unroll
        for (int ms = 0; ms < 2; ++ms)
#pragma unroll
            for (int ns = 0; ns < 2; ++ns)
#pragma unroll
                for (int r = 0; r < 16; ++r) {
                    int rowr = (r & 3) + 8 * (r >> 2) + 4 * hi;
                    dst[(ms * 32 + rowr) * 64 + ns * 32 + col] = acc[ms][ns][r];
                }
    }
    __syncthreads();
    if (w < 2) {
        float* src = red + w * 4096;
#pragma unroll
        for (int ms = 0; ms < 2; ++ms)
#pragma unroll
            for (int ns = 0; ns < 2; ++ns)
#pragma unroll
                for (int r = 0; r < 16; ++r) {
                    int rowr = (r & 3) + 8 * (r >> 2) + 4 * hi;
                    acc[ms][ns][r] += src[(ms * 32 + rowr) * 64 + ns * 32 + col];
                }
    }
    __syncthreads();
    if (w == 1) {
#pragma unroll
        for (int ms = 0; ms < 2; ++ms)
#pragma unroll
            for (int ns = 0; ns < 2; ++ns)
#pragma unroll
                for (int r = 0; r < 16; ++r) {
                    int rowr = (r & 3) + 8 * (r >> 2) + 4 * hi;
                    red[(ms * 32 + rowr) * 64 + ns * 32 + col] = acc[ms][ns][r];
                }
    }
    __syncthreads();
    if (w == 0) {
#pragma unroll
        for (int ms = 0; ms < 2; ++ms)
#pragma unroll
            for (int ns = 0; ns < 2; ++ns)
#pragma unroll
                for (int r = 0; r < 16; ++r) {
                    int rowr = (r & 3) + 8 * (r >> 2) + 4 * hi;
                    acc[ms][ns][r] += red[(ms * 32 + rowr) * 64 + ns * 32 + col];
                }
        if (EPI == 3) {
            float* dstC = Cout + (size_t)kc * M * N;
#pragma unroll
            for (int ms = 0; ms < 2; ++ms)
#pragma unroll
                for (int ns = 0; ns < 2; ++ns)
#pragma unroll
                    for (int g = 0; g < 4; ++g) {
                        int rowt = ms * 32 + 8 * g + 4 * hi;
                        float4 v = make_float4(acc[ms][ns][4 * g + 0], acc[ms][ns][4 * g + 1],
                                               acc[ms][ns][4 * g + 2], acc[ms][ns][4 * g + 3]);
                        *(float4*)&dstC[(size_t)(bn * 64 + ns * 32 + col) * M + bm * 64 + rowt] = v;
                    }
        }
        if (EPI == 4) {
#pragma unroll
            for (int ms = 0; ms < 2; ++ms)
#pragma unroll
                for (int ns = 0; ns < 2; ++ns)
#pragma unroll
                    for (int r = 0; r < 16; ++r) {
                        int rowr = (r & 3) + 8 * (r >> 2) + 4 * hi;
                        red[(ms * 32 + rowr) * 64 + ns * 32 + col] = acc[ms][ns][r];
                    }
        }
    }
    if (EPI == 4) {
        __syncthreads();
        int row = tid >> 2, q = tid & 3;
        int grow = bm * 64 + row;
        const float* xrow = Xf + (size_t)grow * 512 + bn * 64 + q * 16;
        const float* yr = &red[row * 64 + q * 16];
        float s = 0.0f;
#pragma unroll
        for (int j4 = 0; j4 < 4; ++j4) {
            float4 x = *(const float4*)&xrow[j4 * 4];
            s += x.x * yr[j4 * 4 + 0] + x.y * yr[j4 * 4 + 1] +
                 x.z * yr[j4 * 4 + 2] + x.w * yr[j4 * 4 + 3];
        }
        s += __shfl_xor(s, 1, 64);
        s += __shfl_xor(s, 2, 64);
        if (q == 0) atomicAdd(&accOut[grow], s / (4.0f * magv[grow]));
    }
}

// ================= launcher =================
extern "C" void kernel_launch(void* const* d_in, const int* in_sizes, int n_in,
                              void* d_out, int out_size, void* d_ws, size_t ws_size,
                              hipStream_t stream)
{
    const float* X = (const float*)d_in[0];
    const float* chang = (const float*)d_in[1];
    const float* kang = (const float*)d_in[2];
    const float* cent = (const float*)d_in[3];
    const float* kent = (const float*)d_in[4];
    float* out = (float*)d_out;

    size_t off = 0;
    auto alloc = [&](size_t bytes) -> char* {
        char* p = (char*)d_ws + off;
        off += (bytes + 255) & ~(size_t)255;
        return p;
    };
    float* bufT = (float*)alloc(2048 * 512 * 4);            // T0 fp32
    float* Pa = (float*)alloc(8 * 512 * 512 * 4);           // split-K partials (8MB)
    float* C128 = (float*)alloc(2 * 128 * 128 * 4);
    float* K16 = (float*)alloc(2 * 16 * 16 * 4);
    float* mag = (float*)alloc(8192 * 4);
    unsigned short* T0hi = (unsigned short*)alloc(512 * 2048 * 2);
    unsigned short* T0lo = (unsigned short*)alloc(512 * 2048 * 2);
    unsigned short* T1hi = (unsigned short*)alloc(512 * 2048 * 2);
    unsigned short* T1lo = (unsigned short*)alloc(512 * 2048 * 2);
    unsigned short* TPhi = (unsigned short*)alloc(512 * 2048 * 2);
    unsigned short* TPlo = (unsigned short*)alloc(512 * 2048 * 2);
    unsigned short* Ghi = (unsigned short*)alloc(512 * 512 * 2);
    unsigned short* Glo = (unsigned short*)alloc(512 * 512 * 2);
    unsigned short* Xhi = (unsigned short*)alloc(8192 * 512 * 2);
    unsigned short* Xlo = (unsigned short*)alloc(8192 * 512 * 2);
    unsigned short* keHi = (unsigned short*)alloc(2048 * 2048 * 2);
    unsigned short* keLo = (unsigned short*)alloc(2048 * 2048 * 2);
    unsigned short* cehi = (unsigned short*)alloc(2048 * 2048 * 2);
    unsigned short* celo = (unsigned short*)alloc(2048 * 2048 * 2);
    (void)ws_size;

    prep_kernel<<<6208, 256, 0, stream>>>(X, chang, kang, cent, kent,
                                          keHi, keLo, cehi, celo,
                                          Xhi, Xlo, mag, out, bufT, C128, K16);
    transpose_convert_kernel<<<dim3(32, 8), 256, 0, stream>>>(bufT, K16 + 256, T0hi, T0lo); // +kr1

    const int CS = 2048 * 512;   // chain partial chunk size (floats)
    // G1: kent @ T -> partials -> hi/lo (standalone reduce: GEMM consumer)
    gemm_hl_kernel<3><<<dim3(32, 8, 2), 256, 0, stream>>>(
        keHi, keLo, 2048, T0hi, T0lo, 2048, Pa, nullptr, nullptr, nullptr, 2048, 512, 1024);
    reduce_hl_kernel<<<1024, 256, 0, stream>>>(Pa, 2, CS, T1hi, T1lo, nullptr, nullptr, 0);
    // G2: cent @ T -> partials (chrot consumes the pair directly)
    gemm_hl_kernel<3><<<dim3(32, 8, 2), 256, 0, stream>>>(
        cehi, celo, 2048, T1hi, T1lo, 2048, Pa, nullptr, nullptr, nullptr, 2048, 512, 1024);
    chrot_t_kernel<<<512, 256, 0, stream>>>(C128 + 16384, K16, Pa, Pa + CS, T0hi, T0lo);   // ch1 + kr0
    // G3: kent @ T
    gemm_hl_kernel<3><<<dim3(32, 8, 2), 256, 0, stream>>>(
        keHi, keLo, 2048, T0hi, T0lo, 2048, Pa, nullptr, nullptr, nullptr, 2048, 512, 1024);
    reduce_hl_kernel<<<1024, 256, 0, stream>>>(Pa, 2, CS, T1hi, T1lo, nullptr, nullptr, 0);
    // G4: cent @ T -> partials (chrot consumes the pair)
    gemm_hl_kernel<3><<<dim3(32, 8, 2), 256, 0, stream>>>(
        cehi, celo, 2048, T1hi, T1lo, 2048, Pa, nullptr, nullptr, nullptr, 2048, 512, 1024);
    chrot_t_kernel<<<512, 256, 0, stream>>>(C128, nullptr, Pa, Pa + CS, T0hi, T0lo);        // ch0
    // G5: cent @ T -> partials -> hi/lo + parity copy
    gemm_hl_kernel<3><<<dim3(32, 8, 2), 256, 0, stream>>>(
        cehi, celo, 2048, T0hi, T0lo, 2048, Pa, nullptr, nullptr, nullptr, 2048, 512, 1024);
    reduce_hl_kernel<<<1024, 256, 0, stream>>>(Pa, 2, CS, T1hi, T1lo, TPhi, TPlo, 2047);
    // ghat: split-K=8 -> reduce -> Ghi/Glo
    gemm_hl_kernel<3><<<dim3(8, 8, 8), 256, 0, stream>>>(
        T1hi, T1lo, 2048, TPhi, TPlo, 2048, Pa, nullptr, nullptr, nullptr, 512, 512, 256);
    reduce_hl_kernel<<<256, 256, 0, stream>>>(Pa, 8, 512 * 512, Ghi, Glo, nullptr, nullptr, 0);
    // final: fused X@G^T row-dot, scaled by 1/(4*mag), atomicAdd into out
    gemm_hl_kernel<4><<<dim3(128, 8, 1), 256, 0, stream>>>(
        Xhi, Xlo, 512, Ghi, Glo, 512, nullptr, X, mag, out, 8192, 512, 512);
}